// Round 3
// baseline (471.404 us; speedup 1.0000x reference)
//
#include <hip/hip_runtime.h>
#include <math.h>

// AttentionDecoder R10: TWO kernels (launch overhead ~15us each dominates).
// K1 k_scorev: block0 computes v (publishes via threadfence+dual-magic flag);
//   others issue cand loads first, spin w/ TIMEOUT-FALLBACK (recompute v,
//   bit-identical => correct either way, deadlock impossible). Blocks 1..9
//   zero hist/scal. Proven GEMV core unchanged.
// K2 k_tail: 49 co-resident blocks, spin barriers (R7-proven fence+counter):
//   LDS chunk + hist + Z | bar | blk0 scan->u_lo | flag | gather from LDS |
//   bar | blk0 fin (select, renorm, rewrite, threefry-gumbel categorical).
// Model from R7/R8/R9 fits: F~100-135us fixed re-poison, L~15us/launch,
// score ~30us, tail work ~12us. Cut launches 6->2.

#define CAP 4096
#define MAXB 128
#define NEG_INF (-__builtin_inff())
#define VMAGIC0 0x9E3779B9u
#define VMAGIC1 0x85EBCA6Bu

// order-preserving float->uint mapping (monotone increasing)
__device__ __forceinline__ unsigned int f2ord(float f){
  unsigned int b = __float_as_uint(f);
  return (b & 0x80000000u) ? ~b : (b | 0x80000000u);
}
__device__ __forceinline__ unsigned int rotl32(unsigned int x, int d){
  return (x << d) | (x >> (32 - d));
}

// JAX partitionable threefry, key (0,42): x0=idx>>32(=0), x1=idx; bits=w0^w1.
// gumbel = -log(-log(u)), u = bitcast((bits>>9)|0x3f800000)-1 clamped to tiny.
__device__ float gumbel_from_idx(unsigned int idx){
  unsigned int x0 = 0u, x1 = idx;
  const unsigned int ks0 = 0u, ks1 = 42u;
  const unsigned int ks2 = 0u ^ 42u ^ 0x1BD11BDAu;
  x0 += ks0; x1 += ks1;
#define TF_RND(r) { x0 += x1; x1 = rotl32(x1, (r)); x1 ^= x0; }
  TF_RND(13) TF_RND(15) TF_RND(26) TF_RND(6)
  x0 += ks1; x1 += ks2 + 1u;
  TF_RND(17) TF_RND(29) TF_RND(16) TF_RND(24)
  x0 += ks2; x1 += ks0 + 2u;
  TF_RND(13) TF_RND(15) TF_RND(26) TF_RND(6)
  x0 += ks0; x1 += ks1 + 3u;
  TF_RND(17) TF_RND(29) TF_RND(16) TF_RND(24)
  x0 += ks1; x1 += ks2 + 4u;
  TF_RND(13) TF_RND(15) TF_RND(26) TF_RND(6)
  x0 += ks2; x1 += ks0 + 5u;
#undef TF_RND
  unsigned int bits = x0 ^ x1;
  unsigned int fb = (bits >> 9) | 0x3f800000u;
  float f = __uint_as_float(fb) - 1.0f;
  float u = (f < 1.17549435e-38f) ? 1.17549435e-38f : f;
  return -logf(-logf(u));
}

// v = Wk^T (Wq [cur;ctx]) into vsh[128]. Deterministic: identical op order on
// every block that runs it (fallback bitwise == block0's published value).
__device__ void compute_v_shared(const float* __restrict__ cur,
    const float* __restrict__ ctx, const float* __restrict__ Wq,
    const float* __restrict__ Wk, float* q, float* vpart, float* vsh){
  int t = threadIdx.x;
  int lane = t & 63, wave = t >> 6;
  int hl = lane & 31, hi = lane >> 5;
  float4 cb0 = ((const float4*)cur)[hl];
  float4 cb1 = ((const float4*)ctx)[hl];
  const float4* Wq4 = (const float4*)Wq;
  #pragma unroll 4
  for (int i = 0; i < 16; ++i){
    int row = wave * 32 + 2 * i + hi;          // 4 waves x 16 x 2 rows = 128
    float4 w0 = Wq4[row * 64 + hl];
    float4 w1 = Wq4[row * 64 + 32 + hl];
    float d = fmaf(w0.x, cb0.x, fmaf(w0.y, cb0.y, fmaf(w0.z, cb0.z, w0.w * cb0.w)));
    d = fmaf(w1.x, cb1.x, fmaf(w1.y, cb1.y, fmaf(w1.z, cb1.z, fmaf(w1.w, cb1.w, d))));
    d += __shfl_xor(d, 1, 64);
    d += __shfl_xor(d, 2, 64);
    d += __shfl_xor(d, 4, 64);
    d += __shfl_xor(d, 8, 64);
    d += __shfl_xor(d, 16, 64);
    if (hl == 0) q[row] = d;
  }
  __syncthreads();
  int col = t & 127, half = t >> 7;
  const float* wkp = Wk + half * 64 * 128 + col;
  const float* qp  = q + half * 64;
  float acc = 0.f;
  #pragma unroll 8
  for (int h = 0; h < 64; ++h) acc = fmaf(qp[h], wkp[h * 128], acc);
  vpart[t] = acc;
  __syncthreads();
  if (t < 128) vsh[t] = vpart[t] + vpart[t + 128];
}

// K1: fused prep+score. Half-wave per row (32 lanes x float4 = 512B row),
// 16 rows/wave, 64 rows/block. 8 loads in flight before v-phase. No atomics.
__global__ __launch_bounds__(256) void k_scorev(const float* __restrict__ cur,
    const float* __restrict__ ctx, const float* __restrict__ Wq,
    const float* __restrict__ Wk, const float* __restrict__ cand,
    const int* __restrict__ mask, float* __restrict__ v_g,
    unsigned int* __restrict__ vflag, unsigned int* __restrict__ scal_u,
    unsigned int* __restrict__ hist, float* __restrict__ scores,
    float* __restrict__ out, int N){
  const float NLOG = logf(1e-10f);
  __shared__ float vsh[128];
  __shared__ float q[128];
  __shared__ float vpart[256];
  __shared__ int flag_sh;
  int t = threadIdx.x;
  int lane = t & 63, wave = t >> 6;
  int hi = lane >> 5, hl = lane & 31;
  const float4* cp = (const float4*)cand;
  int base = (blockIdx.x * 4 + wave) * 16;
  float4 c[8];
  #pragma unroll
  for (int k = 0; k < 8; ++k){                 // phase 1: 8 loads in flight
    int r = base + 2 * k + hi;
    r = (r < N) ? r : (N - 1);                 // clamp: load stays unconditional
    c[k] = cp[(size_t)r * 32 + hl];
  }
  // housekeeping for K2 while loads fly (K1 completes before K2 launches)
  if (gridDim.x >= 16){
    if (blockIdx.x >= 1 && blockIdx.x <= 8) hist[(blockIdx.x - 1) * 256 + t] = 0u;
    if (blockIdx.x == 9 && t < 16) scal_u[t] = 0u;
  } else if (blockIdx.x == 0){
    for (int k = t; k < 2048; k += 256) hist[k] = 0u;
    if (t < 16) scal_u[t] = 0u;
  }
  // ---- obtain v ----
  if (blockIdx.x == 0){
    compute_v_shared(cur, ctx, Wq, Wk, q, vpart, vsh);
    __syncthreads();
    if (t < 128) v_g[t] = vsh[t];
    __syncthreads();                           // barrier drains stores
    if (t == 0){
      __threadfence();
      __hip_atomic_store(&vflag[0], VMAGIC0, __ATOMIC_RELEASE, __HIP_MEMORY_SCOPE_AGENT);
      __hip_atomic_store(&vflag[1], VMAGIC1, __ATOMIC_RELEASE, __HIP_MEMORY_SCOPE_AGENT);
    }
  } else {
    if (t == 0){
      int ok = 0;
      for (int it = 0; it < 100; ++it){        // ~<30us worst; normal exit <4us
        unsigned int a = __hip_atomic_load(&vflag[0], __ATOMIC_ACQUIRE, __HIP_MEMORY_SCOPE_AGENT);
        unsigned int b = __hip_atomic_load(&vflag[1], __ATOMIC_ACQUIRE, __HIP_MEMORY_SCOPE_AGENT);
        if (a == VMAGIC0 && b == VMAGIC1){ ok = 1; break; }
        __builtin_amdgcn_s_sleep(4);
      }
      flag_sh = ok;
    }
    __syncthreads();
    if (flag_sh){
      if (t < 128) vsh[t] = v_g[t];
    } else {
      compute_v_shared(cur, ctx, Wq, Wk, q, vpart, vsh);  // bit-identical
    }
    __syncthreads();
  }
  float4 v4 = ((const float4*)vsh)[hl];
  // ---- proven consume/reduce/write ----
  float p[8];
  #pragma unroll
  for (int k = 0; k < 8; ++k)
    p[k] = fmaf(c[k].x, v4.x, fmaf(c[k].y, v4.y, fmaf(c[k].z, v4.z, c[k].w * v4.w)));
  #pragma unroll
  for (int k = 0; k < 8; ++k){                 // 8 independent 5-shfl chains
    p[k] += __shfl_xor(p[k], 1, 64);
    p[k] += __shfl_xor(p[k], 2, 64);
    p[k] += __shfl_xor(p[k], 4, 64);
    p[k] += __shfl_xor(p[k], 8, 64);
    p[k] += __shfl_xor(p[k], 16, 64);
  }
  float sv = p[0];
  #pragma unroll
  for (int k = 1; k < 8; ++k) sv = (hl == k) ? p[k] : sv;
  if (hl < 8){                                 // writer lanes
    int r = base + 2 * hl + hi;
    if (r < N) scores[r] = mask[r] ? sv : NEG_INF;
  }
  if (t < 16){                                 // default output value, float4
    int o4 = blockIdx.x * 16 + t;
    if (o4 * 4 + 3 < N){
      ((float4*)out)[o4] = make_float4(NLOG, NLOG, NLOG, NLOG);
    } else {
      #pragma unroll
      for (int e = 0; e < 4; ++e){ int i = o4 * 4 + e; if (i < N) out[i] = NLOG; }
    }
  }
}

// K2: nb (<=49) co-resident blocks, 1024 thr. scal: [3]=Z [5]=u_lo [8]=bar1
// [9]=u_ready [10]=bar2 (zeroed by K1). Chunk lives in LDS across phases.
__global__ __launch_bounds__(1024) void k_tail(const float* __restrict__ scores,
    unsigned int* __restrict__ scal_u, unsigned int* __restrict__ hist,
    float* __restrict__ zpart, unsigned int* __restrict__ cnt,
    unsigned int* __restrict__ buf_idx, float* __restrict__ buf_s,
    float* __restrict__ out, int N, int ktop, int nb){
  __shared__ float sch[4096];                  // chunk; reused as s_lds in fin
  __shared__ unsigned int lh[2048];
  __shared__ unsigned int ich[4096];           // i_lds (fin)
  __shared__ unsigned int suf[256];
  __shared__ unsigned int cnt_l[MAXB], offs[MAXB];
  __shared__ float wred[16];
  __shared__ float rv[16], rl[16];
  __shared__ unsigned int ri[16];
  __shared__ float Z_sh, thr_sh, lnD_sh;
  __shared__ unsigned int u_lo_sh;
  __shared__ int csel_sh, pos_sh, C_sh;
  int t = threadIdx.x, b = blockIdx.x;
  int lane = t & 63, wave = t >> 6;
  for (int k = t; k < 2048; k += 1024) lh[k] = 0u;
  if (t == 0) pos_sh = 0;
  __syncthreads();
  // ---- phase 1: load chunk -> LDS, hist, Z ----
  int base = b * 4096;
  float ez = 0.f;
  {
    int i0 = base + 4 * t;
    float4 s4 = make_float4(NEG_INF, NEG_INF, NEG_INF, NEG_INF);
    if (i0 + 3 < N) s4 = ((const float4*)scores)[(base >> 2) + t];
    else {
      if (i0     < N) s4.x = scores[i0];
      if (i0 + 1 < N) s4.y = scores[i0 + 1];
      if (i0 + 2 < N) s4.z = scores[i0 + 2];
      if (i0 + 3 < N) s4.w = scores[i0 + 3];
    }
    sch[4 * t]     = s4.x;
    sch[4 * t + 1] = s4.y;
    sch[4 * t + 2] = s4.z;
    sch[4 * t + 3] = s4.w;
#define HVISIT(s_) { float sx = (s_); if (sx > NEG_INF){ \
    atomicAdd(&lh[f2ord(sx) >> 21], 1u); ez += expf(sx); } }
    HVISIT(s4.x) HVISIT(s4.y) HVISIT(s4.z) HVISIT(s4.w)
#undef HVISIT
  }
  #pragma unroll
  for (int off = 32; off; off >>= 1) ez += __shfl_xor(ez, off, 64);
  if (lane == 0) wred[wave] = ez;
  __syncthreads();                             // lh + wred complete
  for (int k = t; k < 2048; k += 1024){        // flush: chains <= nb (~49)
    unsigned int cc = lh[k];
    if (cc) atomicAdd(&hist[k], cc);
  }
  __syncthreads();                             // barrier drains atomics (vmcnt)
  if (t == 0){
    float z = 0.f;
    for (int w = 0; w < 16; ++w) z += wred[w];
    zpart[b] = z;
    __threadfence();
    atomicAdd(&scal_u[8], 1u);                 // bar1 arrive (chain <= nb)
  }
  // ---- mid: block 0 scans; others wait on u_ready ----
  if (b == 0){
    if (t == 0){
      while (__hip_atomic_load(&scal_u[8], __ATOMIC_ACQUIRE, __HIP_MEMORY_SCOPE_AGENT)
             < (unsigned)nb) __builtin_amdgcn_s_sleep(2);
      csel_sh = -1;
    }
    __syncthreads();
    float z = (t < nb) ? zpart[t] : 0.f;       // nb <= 128 -> waves 0,1
    if (t < 128){
      #pragma unroll
      for (int off = 32; off; off >>= 1) z += __shfl_xor(z, off, 64);
      if (lane == 0) wred[wave] = z;
    }
    if (t < 256){
      unsigned int csum = 0;
      #pragma unroll
      for (int k = 0; k < 8; ++k) csum += hist[t * 8 + k];
      suf[t] = csum;
    }
    __syncthreads();
    if (t == 0) Z_sh = wred[0] + wred[1];
    for (int d = 1; d < 256; d <<= 1){
      unsigned int add = 0u;
      if (t < 256 && t + d < 256) add = suf[t + d];
      __syncthreads();
      if (t < 256) suf[t] += add;
      __syncthreads();
    }
    if (t < 256){
      unsigned int st = suf[t];
      unsigned int sn = (t < 255) ? suf[t + 1] : 0u;
      if (st >= (unsigned)ktop && sn < (unsigned)ktop) csel_sh = t;   // unique
    }
    __syncthreads();
    if (t == 0){
      int b_sel = 0;
      if (csel_sh >= 0){
        int c = csel_sh;
        unsigned int cum = (c < 255) ? suf[c + 1] : 0u;
        for (int bi = 8 * c + 7; bi >= 8 * c; --bi){
          cum += hist[bi];
          if (cum >= (unsigned)ktop){ b_sel = bi; break; }
        }
      }
      u_lo_sh = ((unsigned int)b_sel) << 21;
      scal_u[5] = u_lo_sh;
      __threadfence();
      __hip_atomic_store(&scal_u[9], 1u, __ATOMIC_RELEASE, __HIP_MEMORY_SCOPE_AGENT);
    }
    __syncthreads();
  } else {
    if (t == 0){
      while (__hip_atomic_load(&scal_u[9], __ATOMIC_ACQUIRE, __HIP_MEMORY_SCOPE_AGENT)
             == 0u) __builtin_amdgcn_s_sleep(2);
      u_lo_sh = scal_u[5];
    }
    __syncthreads();
  }
  // ---- gather from LDS chunk into per-block global region ----
  unsigned int u_lo = u_lo_sh;
  for (int j = t; j < 4096; j += 1024){
    float sx = sch[j];
    if (sx > NEG_INF && f2ord(sx) >= u_lo){
      int p = atomicAdd(&pos_sh, 1);
      if (p < 4096){
        buf_s[b * 4096 + p] = sx;
        buf_idx[b * 4096 + p] = (unsigned int)(base + j);
      }
    }
  }
  __syncthreads();                             // drains buf stores
  if (t == 0){
    cnt[b] = (unsigned int)((pos_sh > 4096) ? 4096 : pos_sh);
    __threadfence();
    atomicAdd(&scal_u[10], 1u);                // bar2 arrive
  }
  if (b != 0) return;
  if (t == 0){
    while (__hip_atomic_load(&scal_u[10], __ATOMIC_ACQUIRE, __HIP_MEMORY_SCOPE_AGENT)
           < (unsigned)nb) __builtin_amdgcn_s_sleep(2);
  }
  __syncthreads();
  // ---- fin: block 0, O(C) work ----
  float* s_lds = sch;
  unsigned int* i_lds = ich;
  if (t < nb) cnt_l[t] = cnt[t];
  if (t == 0) thr_sh = NEG_INF;
  __syncthreads();
  if (t == 0){
    unsigned int acc = 0;
    for (int b2 = 0; b2 < nb; ++b2){ offs[b2] = acc; acc += cnt_l[b2]; }
    C_sh = (acc > CAP) ? CAP : (int)acc;
  }
  __syncthreads();
  for (int b2 = 0; b2 < nb; ++b2){
    unsigned int cb = cnt_l[b2], ob = offs[b2];
    for (unsigned int j = t; j < cb; j += 1024){
      unsigned int p = ob + j;
      if (p < CAP){ s_lds[p] = buf_s[b2 * 4096 + j]; i_lds[p] = buf_idx[b2 * 4096 + j]; }
    }
  }
  __syncthreads();
  int C = C_sh;
  if (C > ktop){                               // exact rank-select, broadcast LDS
    for (int j = t; j < C; j += 1024){
      float sj = s_lds[j];
      int g = 0, e = 0;
      for (int k2 = 0; k2 < C; ++k2){
        float sk = s_lds[k2];
        g += (sk > sj);
        e += (sk == sj);
      }
      if (g < ktop && g + e >= ktop) thr_sh = sj;   // all writers same value
    }
  }
  __syncthreads();
  float s_thr = thr_sh;
  float part = 0.f;
  for (int j = t; j < C; j += 1024){
    float sj = s_lds[j];
    if (sj >= s_thr) part += expf(sj);
  }
  #pragma unroll
  for (int off = 32; off; off >>= 1) part += __shfl_xor(part, off, 64);
  if (lane == 0) wred[wave] = part;
  __syncthreads();
  if (t == 0){
    float T = 0.f;
    for (int w = 0; w < 16; ++w) T += wred[w];
    lnD_sh = logf(T + 1e-10f * Z_sh);          // D = Z*(sum_top p + 1e-10)
  }
  __syncthreads();
  float lnD = lnD_sh;
  for (int j = t; j < C; j += 1024){           // rewrite included entries
    float sj = s_lds[j];
    if (sj >= s_thr) out[i_lds[j]] = logf(expf(sj - lnD) + 1e-10f);
  }
  float bestv = NEG_INF, bestlogit = NEG_INF;  // gumbel categorical
  unsigned int bestidx = 0xFFFFFFFFu;
  for (int j = t; j < C; j += 1024){
    float sj = s_lds[j];
    if (sj >= s_thr){
      unsigned int idx = i_lds[j];
      float logit = sj - lnD;                  // log(filtered)
      float val = logit + gumbel_from_idx(idx);
      if (val > bestv || (val == bestv && idx < bestidx)){
        bestv = val; bestlogit = logit; bestidx = idx;
      }
    }
  }
  #pragma unroll
  for (int off = 32; off; off >>= 1){
    float ov = __shfl_xor(bestv, off, 64);
    float ol = __shfl_xor(bestlogit, off, 64);
    unsigned int oi = (unsigned int)__shfl_xor((int)bestidx, off, 64);
    if (ov > bestv || (ov == bestv && oi < bestidx)){
      bestv = ov; bestlogit = ol; bestidx = oi;
    }
  }
  if (lane == 0){ rv[wave] = bestv; rl[wave] = bestlogit; ri[wave] = bestidx; }
  __syncthreads();
  if (t == 0){
    for (int w = 1; w < 16; ++w){
      if (rv[w] > rv[0] || (rv[w] == rv[0] && ri[w] < ri[0])){
        rv[0] = rv[w]; rl[0] = rl[w]; ri[0] = ri[w];
      }
    }
    out[N] = rl[0];                 // log_prob_action
    out[N + 1] = (float)ri[0];      // action_idx
  }
}

extern "C" void kernel_launch(void* const* d_in, const int* in_sizes, int n_in,
                              void* d_out, int out_size, void* d_ws, size_t ws_size,
                              hipStream_t stream){
  const float* cur  = (const float*)d_in[0];
  const float* ctx  = (const float*)d_in[1];
  const float* cand = (const float*)d_in[2];
  const float* Wq   = (const float*)d_in[3];
  const float* Wk   = (const float*)d_in[4];
  const int*   mask = (const int*)d_in[5];
  int N = in_sizes[5];
  float* out = (float*)d_out;

  char* ws = (char*)d_ws;
  unsigned int* scal_u  = (unsigned int*)ws;                  // 64B ([8..10]=bars)
  unsigned int* vflag   = (unsigned int*)(ws + 256);          // 8B, NEVER zeroed
  float*        v_g     = (float*)(ws + 512);                 // 512B
  float*        zpart   = (float*)(ws + 1024);                // MAXB*4
  unsigned int* cnt     = (unsigned int*)(ws + 1536);         // MAXB*4
  unsigned int* hist    = (unsigned int*)(ws + 4096);         // 8KB
  float*        scores  = (float*)(ws + 16384);               // N*4, 16B-aligned
  char*         bufbase = ws + 16384 + (((size_t)N * 4 + 255) & ~255ull);
  float*        buf_s   = (float*)bufbase;                    // MAXB*4096*4
  unsigned int* buf_idx = (unsigned int*)(bufbase + (size_t)MAXB * 4096 * 4);

  int ktop = N / 2; if (ktop < 1) ktop = 1; if (ktop > 50) ktop = 50;
  int g_score = (N + 63) / 64;          // one 64-row tile per block
  int nb = (N + 4095) / 4096;           // 49 for N=200000
  if (nb > MAXB) nb = MAXB;             // (N fixed at 200000; guard only)

  k_scorev<<<g_score, 256, 0, stream>>>(cur, ctx, Wq, Wk, cand, mask,
                                        v_g, vflag, scal_u, hist, scores, out, N);
  k_tail<<<nb, 1024, 0, stream>>>(scores, scal_u, hist, zpart, cnt,
                                  buf_idx, buf_s, out, N, ktop, nb);
}

// Round 4
// 220.793 us; speedup vs baseline: 2.1351x; 2.1351x over previous
//
#include <hip/hip_runtime.h>
#include <math.h>

// AttentionDecoder R11: 3 kernels.
// prep (1 blk, wave-parallel MLP + zero hist/scal) | score (proven GEMV +
// mask-skip: only load cand rows with mask!=0, halves cand traffic) |
// tail (R10's proven fused hist+scan+gather+fin, 49 co-resident blocks).
// R10 lesson: NEVER have O(grid) blocks spin on one global address (335us
// disaster). Spin barriers only among tens of co-resident blocks (tail: ok).
// Model: F~95us fixed re-poison in timed region, L~11us/launch, score HBM
// floor ~8us (LLC absorbs half of cand), tail work ~15us.

#define CAP 4096
#define MAXB 128
#define NEG_INF (-__builtin_inff())

// order-preserving float->uint mapping (monotone increasing)
__device__ __forceinline__ unsigned int f2ord(float f){
  unsigned int b = __float_as_uint(f);
  return (b & 0x80000000u) ? ~b : (b | 0x80000000u);
}
__device__ __forceinline__ unsigned int rotl32(unsigned int x, int d){
  return (x << d) | (x >> (32 - d));
}

// JAX partitionable threefry, key (0,42): x0=idx>>32(=0), x1=idx; bits=w0^w1.
// gumbel = -log(-log(u)), u = bitcast((bits>>9)|0x3f800000)-1 clamped to tiny.
__device__ float gumbel_from_idx(unsigned int idx){
  unsigned int x0 = 0u, x1 = idx;
  const unsigned int ks0 = 0u, ks1 = 42u;
  const unsigned int ks2 = 0u ^ 42u ^ 0x1BD11BDAu;
  x0 += ks0; x1 += ks1;
#define TF_RND(r) { x0 += x1; x1 = rotl32(x1, (r)); x1 ^= x0; }
  TF_RND(13) TF_RND(15) TF_RND(26) TF_RND(6)
  x0 += ks1; x1 += ks2 + 1u;
  TF_RND(17) TF_RND(29) TF_RND(16) TF_RND(24)
  x0 += ks2; x1 += ks0 + 2u;
  TF_RND(13) TF_RND(15) TF_RND(26) TF_RND(6)
  x0 += ks0; x1 += ks1 + 3u;
  TF_RND(17) TF_RND(29) TF_RND(16) TF_RND(24)
  x0 += ks1; x1 += ks2 + 4u;
  TF_RND(13) TF_RND(15) TF_RND(26) TF_RND(6)
  x0 += ks2; x1 += ks0 + 5u;
#undef TF_RND
  unsigned int bits = x0 ^ x1;
  unsigned int fb = (bits >> 9) | 0x3f800000u;
  float f = __uint_as_float(fb) - 1.0f;
  float u = (f < 1.17549435e-38f) ? 1.17549435e-38f : f;
  return -logf(-logf(u));
}

// Wave-parallel MLP: q = Wq @ [cur;ctx] (half-wave per row, coalesced float4,
// 5-shfl reduce), then v = Wk^T q (split-K across 2 thread-halves).
// Also zeroes hist + scal for k_tail.
__global__ __launch_bounds__(256) void k_prep(const float* __restrict__ cur,
    const float* __restrict__ ctx, const float* __restrict__ Wq,
    const float* __restrict__ Wk, float* __restrict__ v,
    unsigned int* __restrict__ hist, unsigned int* __restrict__ scal_u){
  __shared__ float q[128];
  __shared__ float vpart[256];
  int t = threadIdx.x;
  int lane = t & 63, wave = t >> 6;
  int hl = lane & 31, hi = lane >> 5;
  for (int k = t; k < 2048; k += 256) hist[k] = 0u;
  if (t < 16) scal_u[t] = 0u;
  float4 cb0 = ((const float4*)cur)[hl];
  float4 cb1 = ((const float4*)ctx)[hl];
  const float4* Wq4 = (const float4*)Wq;
  #pragma unroll 4
  for (int i = 0; i < 16; ++i){
    int row = wave * 32 + 2 * i + hi;          // 4 waves x 16 iters x 2 rows = 128
    float4 w0 = Wq4[row * 64 + hl];            // coalesced 512B per half-wave
    float4 w1 = Wq4[row * 64 + 32 + hl];
    float d = fmaf(w0.x, cb0.x, fmaf(w0.y, cb0.y, fmaf(w0.z, cb0.z, w0.w * cb0.w)));
    d = fmaf(w1.x, cb1.x, fmaf(w1.y, cb1.y, fmaf(w1.z, cb1.z, fmaf(w1.w, cb1.w, d))));
    d += __shfl_xor(d, 1, 64);
    d += __shfl_xor(d, 2, 64);
    d += __shfl_xor(d, 4, 64);
    d += __shfl_xor(d, 8, 64);
    d += __shfl_xor(d, 16, 64);
    if (hl == 0) q[row] = d;
  }
  __syncthreads();
  // v[col] = sum_h q[h]*Wk[h*128+col]; split h-range across two 128-thread halves
  int col = t & 127, half = t >> 7;
  const float* wkp = Wk + half * 64 * 128 + col;
  const float* qp  = q + half * 64;
  float acc = 0.f;
  #pragma unroll 8
  for (int h = 0; h < 64; ++h) acc = fmaf(qp[h], wkp[h * 128], acc);
  vpart[t] = acc;
  __syncthreads();
  if (t < 128) v[t] = vpart[t] + vpart[t + 128];
}

// PURE GEMV + mask-skip. Half-wave per row (32 lanes x float4 = 512B row),
// 16 rows/wave, 64 rows/block. Mask loads first (uniform per half-wave ->
// broadcast); cand row load only when mask!=0 (exec-masked, no traffic for
// skipped rows, ~50% saving). No atomics.
__global__ __launch_bounds__(256) void k_score(const float* __restrict__ cand,
    const int* __restrict__ mask, const float* __restrict__ v,
    float* __restrict__ scores, float* __restrict__ out, int N){
  const float NLOG = logf(1e-10f);
  int t = threadIdx.x;
  int lane = t & 63, wave = t >> 6;
  int hi = lane >> 5, hl = lane & 31;
  float4 v4 = ((const float4*)v)[hl];
  const float4* cp = (const float4*)cand;
  int base = (blockIdx.x * 4 + wave) * 16;
  int m[8];
  #pragma unroll
  for (int k = 0; k < 8; ++k){                 // 8 mask loads in flight
    int r = base + 2 * k + hi;
    r = (r < N) ? r : (N - 1);
    m[k] = mask[r];
  }
  float4 c[8];
  #pragma unroll
  for (int k = 0; k < 8; ++k){                 // masked cand loads in flight
    int r = base + 2 * k + hi;
    r = (r < N) ? r : (N - 1);
    c[k] = make_float4(0.f, 0.f, 0.f, 0.f);
    if (m[k]) c[k] = cp[(size_t)r * 32 + hl];
  }
  float p[8];
  #pragma unroll
  for (int k = 0; k < 8; ++k)                  // consume
    p[k] = fmaf(c[k].x, v4.x, fmaf(c[k].y, v4.y, fmaf(c[k].z, v4.z, c[k].w * v4.w)));
  #pragma unroll
  for (int k = 0; k < 8; ++k){                 // 8 independent 5-shfl chains
    p[k] += __shfl_xor(p[k], 1, 64);
    p[k] += __shfl_xor(p[k], 2, 64);
    p[k] += __shfl_xor(p[k], 4, 64);
    p[k] += __shfl_xor(p[k], 8, 64);
    p[k] += __shfl_xor(p[k], 16, 64);
  }
  float sv = p[0];
  #pragma unroll
  for (int k = 1; k < 8; ++k) sv = (hl == k) ? p[k] : sv;
  if (hl < 8){                                 // writer lanes
    int r = base + 2 * hl + hi;
    int mm = (hl < 8) ? ((hl == 0) ? m[0] : 0) : 0; (void)mm;
    if (r < N) scores[r] = mask[r] ? sv : NEG_INF;
  }
  if (t < 16){                                 // default output value, float4
    int o4 = blockIdx.x * 16 + t;
    if (o4 * 4 + 3 < N){
      ((float4*)out)[o4] = make_float4(NLOG, NLOG, NLOG, NLOG);
    } else {
      #pragma unroll
      for (int e = 0; e < 4; ++e){ int i = o4 * 4 + e; if (i < N) out[i] = NLOG; }
    }
  }
}

// Fused tail: nb (<=49) co-resident blocks, 1024 thr (proven in R10).
// scal: [5]=u_lo [8]=bar1 [9]=u_ready [10]=bar2 (zeroed by k_prep).
// Chunk lives in LDS across phases; spin chains <= nb (~49) only.
__global__ __launch_bounds__(1024) void k_tail(const float* __restrict__ scores,
    unsigned int* __restrict__ scal_u, unsigned int* __restrict__ hist,
    float* __restrict__ zpart, unsigned int* __restrict__ cnt,
    unsigned int* __restrict__ buf_idx, float* __restrict__ buf_s,
    float* __restrict__ out, int N, int ktop, int nb){
  __shared__ float sch[4096];                  // chunk; reused as s_lds in fin
  __shared__ unsigned int lh[2048];
  __shared__ unsigned int ich[4096];           // i_lds (fin)
  __shared__ unsigned int suf[256];
  __shared__ unsigned int cnt_l[MAXB], offs[MAXB];
  __shared__ float wred[16];
  __shared__ float rv[16], rl[16];
  __shared__ unsigned int ri[16];
  __shared__ float Z_sh, thr_sh, lnD_sh;
  __shared__ unsigned int u_lo_sh;
  __shared__ int csel_sh, pos_sh, C_sh;
  int t = threadIdx.x, b = blockIdx.x;
  int lane = t & 63, wave = t >> 6;
  for (int k = t; k < 2048; k += 1024) lh[k] = 0u;
  if (t == 0) pos_sh = 0;
  __syncthreads();
  // ---- phase 1: load chunk -> LDS, hist, Z ----
  int base = b * 4096;
  float ez = 0.f;
  {
    int i0 = base + 4 * t;
    float4 s4 = make_float4(NEG_INF, NEG_INF, NEG_INF, NEG_INF);
    if (i0 + 3 < N) s4 = ((const float4*)scores)[(base >> 2) + t];
    else {
      if (i0     < N) s4.x = scores[i0];
      if (i0 + 1 < N) s4.y = scores[i0 + 1];
      if (i0 + 2 < N) s4.z = scores[i0 + 2];
      if (i0 + 3 < N) s4.w = scores[i0 + 3];
    }
    sch[4 * t]     = s4.x;
    sch[4 * t + 1] = s4.y;
    sch[4 * t + 2] = s4.z;
    sch[4 * t + 3] = s4.w;
#define HVISIT(s_) { float sx = (s_); if (sx > NEG_INF){ \
    atomicAdd(&lh[f2ord(sx) >> 21], 1u); ez += expf(sx); } }
    HVISIT(s4.x) HVISIT(s4.y) HVISIT(s4.z) HVISIT(s4.w)
#undef HVISIT
  }
  #pragma unroll
  for (int off = 32; off; off >>= 1) ez += __shfl_xor(ez, off, 64);
  if (lane == 0) wred[wave] = ez;
  __syncthreads();                             // lh + wred complete
  for (int k = t; k < 2048; k += 1024){        // flush: chains <= nb (~49)
    unsigned int cc = lh[k];
    if (cc) atomicAdd(&hist[k], cc);
  }
  __syncthreads();                             // barrier drains atomics (vmcnt)
  if (t == 0){
    float z = 0.f;
    for (int w = 0; w < 16; ++w) z += wred[w];
    zpart[b] = z;
    __threadfence();
    atomicAdd(&scal_u[8], 1u);                 // bar1 arrive (chain <= nb)
  }
  // ---- mid: block 0 scans; others wait on u_ready ----
  if (b == 0){
    if (t == 0){
      while (__hip_atomic_load(&scal_u[8], __ATOMIC_ACQUIRE, __HIP_MEMORY_SCOPE_AGENT)
             < (unsigned)nb) __builtin_amdgcn_s_sleep(2);
      csel_sh = -1;
    }
    __syncthreads();
    float z = (t < nb) ? zpart[t] : 0.f;       // nb <= 128 -> waves 0,1
    if (t < 128){
      #pragma unroll
      for (int off = 32; off; off >>= 1) z += __shfl_xor(z, off, 64);
      if (lane == 0) wred[wave] = z;
    }
    if (t < 256){
      unsigned int csum = 0;
      #pragma unroll
      for (int k = 0; k < 8; ++k) csum += hist[t * 8 + k];
      suf[t] = csum;
    }
    __syncthreads();
    if (t == 0) Z_sh = wred[0] + wred[1];
    for (int d = 1; d < 256; d <<= 1){
      unsigned int add = 0u;
      if (t < 256 && t + d < 256) add = suf[t + d];
      __syncthreads();
      if (t < 256) suf[t] += add;
      __syncthreads();
    }
    if (t < 256){
      unsigned int st = suf[t];
      unsigned int sn = (t < 255) ? suf[t + 1] : 0u;
      if (st >= (unsigned)ktop && sn < (unsigned)ktop) csel_sh = t;   // unique
    }
    __syncthreads();
    if (t == 0){
      int b_sel = 0;
      if (csel_sh >= 0){
        int c = csel_sh;
        unsigned int cum = (c < 255) ? suf[c + 1] : 0u;
        for (int bi = 8 * c + 7; bi >= 8 * c; --bi){
          cum += hist[bi];
          if (cum >= (unsigned)ktop){ b_sel = bi; break; }
        }
      }
      u_lo_sh = ((unsigned int)b_sel) << 21;
      scal_u[5] = u_lo_sh;
      __threadfence();
      __hip_atomic_store(&scal_u[9], 1u, __ATOMIC_RELEASE, __HIP_MEMORY_SCOPE_AGENT);
    }
    __syncthreads();
  } else {
    if (t == 0){
      while (__hip_atomic_load(&scal_u[9], __ATOMIC_ACQUIRE, __HIP_MEMORY_SCOPE_AGENT)
             == 0u) __builtin_amdgcn_s_sleep(2);
      u_lo_sh = scal_u[5];
    }
    __syncthreads();
  }
  // ---- gather from LDS chunk into per-block global region ----
  unsigned int u_lo = u_lo_sh;
  for (int j = t; j < 4096; j += 1024){
    float sx = sch[j];
    if (sx > NEG_INF && f2ord(sx) >= u_lo){
      int p = atomicAdd(&pos_sh, 1);
      if (p < 4096){
        buf_s[b * 4096 + p] = sx;
        buf_idx[b * 4096 + p] = (unsigned int)(base + j);
      }
    }
  }
  __syncthreads();                             // drains buf stores
  if (t == 0){
    cnt[b] = (unsigned int)((pos_sh > 4096) ? 4096 : pos_sh);
    __threadfence();
    atomicAdd(&scal_u[10], 1u);                // bar2 arrive
  }
  if (b != 0) return;
  if (t == 0){
    while (__hip_atomic_load(&scal_u[10], __ATOMIC_ACQUIRE, __HIP_MEMORY_SCOPE_AGENT)
           < (unsigned)nb) __builtin_amdgcn_s_sleep(2);
  }
  __syncthreads();
  // ---- fin: block 0, O(C) work ----
  float* s_lds = sch;
  unsigned int* i_lds = ich;
  if (t < nb) cnt_l[t] = cnt[t];
  if (t == 0) thr_sh = NEG_INF;
  __syncthreads();
  if (t == 0){
    unsigned int acc = 0;
    for (int b2 = 0; b2 < nb; ++b2){ offs[b2] = acc; acc += cnt_l[b2]; }
    C_sh = (acc > CAP) ? CAP : (int)acc;
  }
  __syncthreads();
  for (int b2 = 0; b2 < nb; ++b2){
    unsigned int cb = cnt_l[b2], ob = offs[b2];
    for (unsigned int j = t; j < cb; j += 1024){
      unsigned int p = ob + j;
      if (p < CAP){ s_lds[p] = buf_s[b2 * 4096 + j]; i_lds[p] = buf_idx[b2 * 4096 + j]; }
    }
  }
  __syncthreads();
  int C = C_sh;
  if (C > ktop){                               // exact rank-select, broadcast LDS
    for (int j = t; j < C; j += 1024){
      float sj = s_lds[j];
      int g = 0, e = 0;
      for (int k2 = 0; k2 < C; ++k2){
        float sk = s_lds[k2];
        g += (sk > sj);
        e += (sk == sj);
      }
      if (g < ktop && g + e >= ktop) thr_sh = sj;   // all writers same value
    }
  }
  __syncthreads();
  float s_thr = thr_sh;
  float part = 0.f;
  for (int j = t; j < C; j += 1024){
    float sj = s_lds[j];
    if (sj >= s_thr) part += expf(sj);
  }
  #pragma unroll
  for (int off = 32; off; off >>= 1) part += __shfl_xor(part, off, 64);
  if (lane == 0) wred[wave] = part;
  __syncthreads();
  if (t == 0){
    float T = 0.f;
    for (int w = 0; w < 16; ++w) T += wred[w];
    lnD_sh = logf(T + 1e-10f * Z_sh);          // D = Z*(sum_top p + 1e-10)
  }
  __syncthreads();
  float lnD = lnD_sh;
  for (int j = t; j < C; j += 1024){           // rewrite included entries
    float sj = s_lds[j];
    if (sj >= s_thr) out[i_lds[j]] = logf(expf(sj - lnD) + 1e-10f);
  }
  float bestv = NEG_INF, bestlogit = NEG_INF;  // gumbel categorical
  unsigned int bestidx = 0xFFFFFFFFu;
  for (int j = t; j < C; j += 1024){
    float sj = s_lds[j];
    if (sj >= s_thr){
      unsigned int idx = i_lds[j];
      float logit = sj - lnD;                  // log(filtered)
      float val = logit + gumbel_from_idx(idx);
      if (val > bestv || (val == bestv && idx < bestidx)){
        bestv = val; bestlogit = logit; bestidx = idx;
      }
    }
  }
  #pragma unroll
  for (int off = 32; off; off >>= 1){
    float ov = __shfl_xor(bestv, off, 64);
    float ol = __shfl_xor(bestlogit, off, 64);
    unsigned int oi = (unsigned int)__shfl_xor((int)bestidx, off, 64);
    if (ov > bestv || (ov == bestv && oi < bestidx)){
      bestv = ov; bestlogit = ol; bestidx = oi;
    }
  }
  if (lane == 0){ rv[wave] = bestv; rl[wave] = bestlogit; ri[wave] = bestidx; }
  __syncthreads();
  if (t == 0){
    for (int w = 1; w < 16; ++w){
      if (rv[w] > rv[0] || (rv[w] == rv[0] && ri[w] < ri[0])){
        rv[0] = rv[w]; rl[0] = rl[w]; ri[0] = ri[w];
      }
    }
    out[N] = rl[0];                 // log_prob_action
    out[N + 1] = (float)ri[0];      // action_idx
  }
}

extern "C" void kernel_launch(void* const* d_in, const int* in_sizes, int n_in,
                              void* d_out, int out_size, void* d_ws, size_t ws_size,
                              hipStream_t stream){
  const float* cur  = (const float*)d_in[0];
  const float* ctx  = (const float*)d_in[1];
  const float* cand = (const float*)d_in[2];
  const float* Wq   = (const float*)d_in[3];
  const float* Wk   = (const float*)d_in[4];
  const int*   mask = (const int*)d_in[5];
  int N = in_sizes[5];
  float* out = (float*)d_out;

  char* ws = (char*)d_ws;
  unsigned int* scal_u  = (unsigned int*)ws;                  // 64B ([8..10]=bars)
  float*        v       = (float*)(ws + 512);                 // 512B
  float*        zpart   = (float*)(ws + 1024);                // MAXB*4
  unsigned int* cnt     = (unsigned int*)(ws + 1536);         // MAXB*4
  unsigned int* hist    = (unsigned int*)(ws + 4096);         // 8KB
  float*        scores  = (float*)(ws + 16384);               // N*4, 16B-aligned
  char*         bufbase = ws + 16384 + (((size_t)N * 4 + 255) & ~255ull);
  float*        buf_s   = (float*)bufbase;                    // MAXB*4096*4
  unsigned int* buf_idx = (unsigned int*)(bufbase + (size_t)MAXB * 4096 * 4);

  int ktop = N / 2; if (ktop < 1) ktop = 1; if (ktop > 50) ktop = 50;
  int g_score = (N + 63) / 64;          // one 64-row tile per block
  int nb = (N + 4095) / 4096;           // 49 for N=200000
  if (nb > MAXB) nb = MAXB;             // (N fixed at 200000; guard only)

  k_prep<<<1, 256, 0, stream>>>(cur, ctx, Wq, Wk, v, hist, scal_u);
  k_score<<<g_score, 256, 0, stream>>>(cand, mask, v, scores, out, N);
  k_tail<<<nb, 1024, 0, stream>>>(scores, scal_u, hist, zpart, cnt,
                                  buf_idx, buf_s, out, N, ktop, nb);
}

// Round 5
// 220.289 us; speedup vs baseline: 2.1399x; 1.0023x over previous
//
#include <hip/hip_runtime.h>
#include <math.h>

// AttentionDecoder R12: 3 kernels, NO inter-block polling anywhere.
// prep (1 blk wave-parallel MLP + zero scal) | score (proven pure GEMV) |
// tail (49 blocks, ONE launch): per-block LOCAL hist+scan -> local top-50
//   superset gather (zero inter-block comms; union of local top-50s contains
//   global top-50 -- proof: for x >= v_global50, #strictly-higher-binned
//   in x's block <= #{>v} <= 49 < 50), then single done-counter; last block
//   re-hists ~2700 candidates in LDS, bin-filters to ~100, exact select, fin.
// Model (fits R7/R8/R9/R11): F~115us fixed resets, L~10us/launch, score~25,
// prep_fast~4. R11 lesson: spin-polling costs ~40us even at 48 blocks ->
// only single-shot done-counter atomics allowed.

#define CAP 4096
#define SLOT 2048
#define MAXB 64
#define C2CAP 2048
#define NEG_INF (-__builtin_inff())

// order-preserving float->uint mapping (monotone increasing)
__device__ __forceinline__ unsigned int f2ord(float f){
  unsigned int b = __float_as_uint(f);
  return (b & 0x80000000u) ? ~b : (b | 0x80000000u);
}
__device__ __forceinline__ unsigned int rotl32(unsigned int x, int d){
  return (x << d) | (x >> (32 - d));
}

// JAX partitionable threefry, key (0,42): x0=idx>>32(=0), x1=idx; bits=w0^w1.
// gumbel = -log(-log(u)), u = bitcast((bits>>9)|0x3f800000)-1 clamped to tiny.
__device__ float gumbel_from_idx(unsigned int idx){
  unsigned int x0 = 0u, x1 = idx;
  const unsigned int ks0 = 0u, ks1 = 42u;
  const unsigned int ks2 = 0u ^ 42u ^ 0x1BD11BDAu;
  x0 += ks0; x1 += ks1;
#define TF_RND(r) { x0 += x1; x1 = rotl32(x1, (r)); x1 ^= x0; }
  TF_RND(13) TF_RND(15) TF_RND(26) TF_RND(6)
  x0 += ks1; x1 += ks2 + 1u;
  TF_RND(17) TF_RND(29) TF_RND(16) TF_RND(24)
  x0 += ks2; x1 += ks0 + 2u;
  TF_RND(13) TF_RND(15) TF_RND(26) TF_RND(6)
  x0 += ks0; x1 += ks1 + 3u;
  TF_RND(17) TF_RND(29) TF_RND(16) TF_RND(24)
  x0 += ks1; x1 += ks2 + 4u;
  TF_RND(13) TF_RND(15) TF_RND(26) TF_RND(6)
  x0 += ks2; x1 += ks0 + 5u;
#undef TF_RND
  unsigned int bits = x0 ^ x1;
  unsigned int fb = (bits >> 9) | 0x3f800000u;
  float f = __uint_as_float(fb) - 1.0f;
  float u = (f < 1.17549435e-38f) ? 1.17549435e-38f : f;
  return -logf(-logf(u));
}

// Shared hist suffix-scan select: lh[2048] counts -> *u_lo_sh = lower edge of
// the bin where cumulative-from-top first reaches ktop (0 if never).
// Caller must set *csel_sh = -1 and __syncthreads() before calling.
// All 1024 threads must call (uniform).
__device__ void hist_select(unsigned int* lh, unsigned int* suf, int* csel_sh,
                            unsigned int* u_lo_sh, int ktop, int t){
  if (t < 256){
    unsigned int csum = 0;
    #pragma unroll
    for (int k = 0; k < 8; ++k) csum += lh[t * 8 + k];
    suf[t] = csum;
  }
  __syncthreads();
  for (int d = 1; d < 256; d <<= 1){
    unsigned int add = 0u;
    if (t < 256 && t + d < 256) add = suf[t + d];
    __syncthreads();
    if (t < 256) suf[t] += add;
    __syncthreads();
  }
  if (t < 256){
    unsigned int st = suf[t];
    unsigned int sn = (t < 255) ? suf[t + 1] : 0u;
    if (st >= (unsigned)ktop && sn < (unsigned)ktop) *csel_sh = t;   // unique
  }
  __syncthreads();
  if (t == 0){
    int b_sel = 0;
    int c = *csel_sh;
    if (c >= 0){
      unsigned int cum = (c < 255) ? suf[c + 1] : 0u;
      for (int bi = 8 * c + 7; bi >= 8 * c; --bi){
        cum += lh[bi];
        if (cum >= (unsigned)ktop){ b_sel = bi; break; }
      }
    }
    *u_lo_sh = ((unsigned int)b_sel) << 21;
  }
  __syncthreads();
}

// Wave-parallel MLP: q = Wq @ [cur;ctx] (half-wave per row, coalesced float4,
// 5-shfl reduce), then v = Wk^T q (split-K across 2 thread-halves).
// Also zeroes scal (done-counter) for k_tail.
__global__ __launch_bounds__(256) void k_prep(const float* __restrict__ cur,
    const float* __restrict__ ctx, const float* __restrict__ Wq,
    const float* __restrict__ Wk, float* __restrict__ v,
    unsigned int* __restrict__ scal_u){
  __shared__ float q[128];
  __shared__ float vpart[256];
  int t = threadIdx.x;
  int lane = t & 63, wave = t >> 6;
  int hl = lane & 31, hi = lane >> 5;
  if (t < 16) scal_u[t] = 0u;
  float4 cb0 = ((const float4*)cur)[hl];
  float4 cb1 = ((const float4*)ctx)[hl];
  const float4* Wq4 = (const float4*)Wq;
  #pragma unroll 4
  for (int i = 0; i < 16; ++i){
    int row = wave * 32 + 2 * i + hi;          // 4 waves x 16 iters x 2 rows = 128
    float4 w0 = Wq4[row * 64 + hl];            // coalesced 512B per half-wave
    float4 w1 = Wq4[row * 64 + 32 + hl];
    float d = fmaf(w0.x, cb0.x, fmaf(w0.y, cb0.y, fmaf(w0.z, cb0.z, w0.w * cb0.w)));
    d = fmaf(w1.x, cb1.x, fmaf(w1.y, cb1.y, fmaf(w1.z, cb1.z, fmaf(w1.w, cb1.w, d))));
    d += __shfl_xor(d, 1, 64);
    d += __shfl_xor(d, 2, 64);
    d += __shfl_xor(d, 4, 64);
    d += __shfl_xor(d, 8, 64);
    d += __shfl_xor(d, 16, 64);
    if (hl == 0) q[row] = d;
  }
  __syncthreads();
  // v[col] = sum_h q[h]*Wk[h*128+col]; split h-range across two 128-thread halves
  int col = t & 127, half = t >> 7;
  const float* wkp = Wk + half * 64 * 128 + col;
  const float* qp  = q + half * 64;
  float acc = 0.f;
  #pragma unroll 8
  for (int h = 0; h < 64; ++h) acc = fmaf(qp[h], wkp[h * 128], acc);
  vpart[t] = acc;
  __syncthreads();
  if (t < 128) v[t] = vpart[t] + vpart[t + 128];
}

// PURE GEMV (proven, no mask-skip). Half-wave per row (32 lanes x float4 =
// 512B row), 16 rows/wave, 64 rows/block. All 8 loads in flight before FMAs.
__global__ __launch_bounds__(256) void k_score(const float* __restrict__ cand,
    const int* __restrict__ mask, const float* __restrict__ v,
    float* __restrict__ scores, float* __restrict__ out, int N){
  const float NLOG = logf(1e-10f);
  int t = threadIdx.x;
  int lane = t & 63, wave = t >> 6;
  int hi = lane >> 5, hl = lane & 31;
  float4 v4 = ((const float4*)v)[hl];
  const float4* cp = (const float4*)cand;
  int base = (blockIdx.x * 4 + wave) * 16;
  float4 c[8];
  #pragma unroll
  for (int k = 0; k < 8; ++k){                 // phase 1: 8 loads in flight
    int r = base + 2 * k + hi;
    r = (r < N) ? r : (N - 1);                 // clamp: load stays unconditional
    c[k] = cp[(size_t)r * 32 + hl];
  }
  float p[8];
  #pragma unroll
  for (int k = 0; k < 8; ++k)                  // phase 2: consume
    p[k] = fmaf(c[k].x, v4.x, fmaf(c[k].y, v4.y, fmaf(c[k].z, v4.z, c[k].w * v4.w)));
  #pragma unroll
  for (int k = 0; k < 8; ++k){                 // 8 independent 5-shfl chains
    p[k] += __shfl_xor(p[k], 1, 64);
    p[k] += __shfl_xor(p[k], 2, 64);
    p[k] += __shfl_xor(p[k], 4, 64);
    p[k] += __shfl_xor(p[k], 8, 64);
    p[k] += __shfl_xor(p[k], 16, 64);
  }
  float sv = p[0];
  #pragma unroll
  for (int k = 1; k < 8; ++k) sv = (hl == k) ? p[k] : sv;
  if (hl < 8){                                 // writer lanes
    int r = base + 2 * hl + hi;
    if (r < N) scores[r] = mask[r] ? sv : NEG_INF;
  }
  if (t < 16){                                 // default output value, float4
    int o4 = blockIdx.x * 16 + t;
    if (o4 * 4 + 3 < N){
      ((float4*)out)[o4] = make_float4(NLOG, NLOG, NLOG, NLOG);
    } else {
      #pragma unroll
      for (int e = 0; e < 4; ++e){ int i = o4 * 4 + e; if (i < N) out[i] = NLOG; }
    }
  }
}

// Single tail launch, nb (<=49) blocks x 1024 thr, NO polling:
// phase 1: chunk->LDS, local hist, Z partial. phase 2: LOCAL scan -> local
// top-ktop bin edge. phase 3: gather local superset -> per-block buf region.
// done-counter (single atomic, no spin); LAST block: collect C (~2700)
// candidates, re-hist in LDS -> global bin edge, compact to C2 (~100),
// exact rank-select, renorm, scatter-rewrite, threefry-gumbel categorical.
__global__ __launch_bounds__(1024) void k_tail(const float* __restrict__ scores,
    unsigned int* __restrict__ scal_u, float* __restrict__ zpart,
    unsigned int* __restrict__ cnt, unsigned int* __restrict__ buf_idx,
    float* __restrict__ buf_s, float* __restrict__ out,
    int N, int ktop, int nb){
  __shared__ float sch[4096];                  // chunk; reused as cand store in fin
  __shared__ unsigned int ich[4096];           // cand indices (fin)
  __shared__ unsigned int lh[2048];
  __shared__ unsigned int suf[256];
  __shared__ float s2[C2CAP];
  __shared__ unsigned int i2[C2CAP];
  __shared__ unsigned int cnt_l[MAXB], offs[MAXB];
  __shared__ float wred[16];
  __shared__ float rv[16], rl[16];
  __shared__ unsigned int ri[16];
  __shared__ float Z_sh, thr_sh, lnD_sh;
  __shared__ unsigned int u_lo_sh;
  __shared__ int csel_sh, pos_sh, C_sh, last_sh;
  int t = threadIdx.x, b = blockIdx.x;
  int lane = t & 63, wave = t >> 6;
  for (int k = t; k < 2048; k += 1024) lh[k] = 0u;
  if (t == 0){ pos_sh = 0; csel_sh = -1; }
  __syncthreads();
  // ---- phase 1: chunk -> LDS, local hist, Z partial ----
  int base = b * 4096;
  float ez = 0.f;
  {
    int i0 = base + 4 * t;
    float4 s4 = make_float4(NEG_INF, NEG_INF, NEG_INF, NEG_INF);
    if (i0 + 3 < N) s4 = ((const float4*)scores)[(base >> 2) + t];
    else {
      if (i0     < N) s4.x = scores[i0];
      if (i0 + 1 < N) s4.y = scores[i0 + 1];
      if (i0 + 2 < N) s4.z = scores[i0 + 2];
    }
    sch[4 * t]     = s4.x;
    sch[4 * t + 1] = s4.y;
    sch[4 * t + 2] = s4.z;
    sch[4 * t + 3] = s4.w;
#define HVISIT(s_) { float sx = (s_); if (sx > NEG_INF){ \
    atomicAdd(&lh[f2ord(sx) >> 21], 1u); ez += expf(sx); } }
    HVISIT(s4.x) HVISIT(s4.y) HVISIT(s4.z) HVISIT(s4.w)
#undef HVISIT
  }
  #pragma unroll
  for (int off = 32; off; off >>= 1) ez += __shfl_xor(ez, off, 64);
  if (lane == 0) wred[wave] = ez;
  __syncthreads();                             // lh + wred complete
  // ---- phase 2: LOCAL suffix scan -> local top-ktop bin edge ----
  hist_select(lh, suf, &csel_sh, &u_lo_sh, ktop, t);
  // ---- phase 3: gather local superset into per-block buf region ----
  unsigned int u_lo = u_lo_sh;
  for (int j = t; j < 4096; j += 1024){
    float sx = sch[j];
    if (sx > NEG_INF && f2ord(sx) >= u_lo){
      int p = atomicAdd(&pos_sh, 1);
      if (p < SLOT){
        buf_s[(size_t)b * SLOT + p] = sx;
        buf_idx[(size_t)b * SLOT + p] = (unsigned int)(base + j);
      }
    }
  }
  __syncthreads();                             // drains buf stores (vmcnt@barrier)
  if (t == 0){
    cnt[b] = (unsigned int)((pos_sh > SLOT) ? SLOT : pos_sh);
    float z = 0.f;
    for (int w = 0; w < 16; ++w) z += wred[w];
    zpart[b] = z;
    __threadfence();
    unsigned int old = atomicAdd(&scal_u[8], 1u);   // single-shot, chain <= nb
    last_sh = (old == (unsigned)(nb - 1));
  }
  __syncthreads();
  if (!last_sh) return;
  __threadfence();
  // ---- fin (last block only): collect candidates ----
  if (t < nb) cnt_l[t] = cnt[t];
  {
    float z = 0.f;
    if (t < 64){
      z = (t < nb) ? zpart[t] : 0.f;
      #pragma unroll
      for (int off = 32; off; off >>= 1) z += __shfl_xor(z, off, 64);
    }
    if (t == 0){ Z_sh = z; thr_sh = NEG_INF; pos_sh = 0; csel_sh = -1; }
  }
  __syncthreads();
  if (t == 0){
    unsigned int acc = 0;
    for (int b2 = 0; b2 < nb; ++b2){ offs[b2] = acc; acc += cnt_l[b2]; }
    C_sh = (acc > CAP) ? CAP : (int)acc;
  }
  __syncthreads();
  for (int b2 = 0; b2 < nb; ++b2){
    unsigned int cb = cnt_l[b2], ob = offs[b2];
    for (unsigned int j = t; j < cb; j += 1024){
      unsigned int p = ob + j;
      if (p < CAP){
        sch[p] = buf_s[(size_t)b2 * SLOT + j];
        ich[p] = buf_idx[(size_t)b2 * SLOT + j];
      }
    }
  }
  for (int k = t; k < 2048; k += 1024) lh[k] = 0u;   // reset hist for round 2
  __syncthreads();
  int C = C_sh;
  // ---- re-hist candidates -> global bin edge (over candidate multiset ==
  // global semantics: all elements >= global-50th are candidates) ----
  for (int j = t; j < C; j += 1024) atomicAdd(&lh[f2ord(sch[j]) >> 21], 1u);
  __syncthreads();
  hist_select(lh, suf, &csel_sh, &u_lo_sh, ktop, t);
  // compact to C2 (~ktop + binmates)
  unsigned int u_lo2 = u_lo_sh;
  for (int j = t; j < C; j += 1024){
    float sx = sch[j];
    if (f2ord(sx) >= u_lo2){
      int p = atomicAdd(&pos_sh, 1);
      if (p < C2CAP){ s2[p] = sx; i2[p] = ich[j]; }
    }
  }
  __syncthreads();
  int C2 = (pos_sh > C2CAP) ? C2CAP : pos_sh;
  // ---- exact rank-select on C2 entries (broadcast LDS reads) ----
  if (C2 > ktop){
    for (int j = t; j < C2; j += 1024){
      float sj = s2[j];
      int g = 0, e = 0;
      for (int k2 = 0; k2 < C2; ++k2){
        float sk = s2[k2];
        g += (sk > sj);
        e += (sk == sj);
      }
      if (g < ktop && g + e >= ktop) thr_sh = sj;   // all writers same value
    }
  }
  __syncthreads();
  float s_thr = thr_sh;
  float part = 0.f;
  for (int j = t; j < C2; j += 1024){
    float sj = s2[j];
    if (sj >= s_thr) part += expf(sj);
  }
  #pragma unroll
  for (int off = 32; off; off >>= 1) part += __shfl_xor(part, off, 64);
  if (lane == 0) wred[wave] = part;
  __syncthreads();
  if (t == 0){
    float T = 0.f;
    for (int w = 0; w < 16; ++w) T += wred[w];
    lnD_sh = logf(T + 1e-10f * Z_sh);          // D = Z*(sum_top p + 1e-10)
  }
  __syncthreads();
  float lnD = lnD_sh;
  for (int j = t; j < C2; j += 1024){          // rewrite included entries
    float sj = s2[j];
    if (sj >= s_thr) out[i2[j]] = logf(expf(sj - lnD) + 1e-10f);
  }
  float bestv = NEG_INF, bestlogit = NEG_INF;  // gumbel categorical
  unsigned int bestidx = 0xFFFFFFFFu;
  for (int j = t; j < C2; j += 1024){
    float sj = s2[j];
    if (sj >= s_thr){
      unsigned int idx = i2[j];
      float logit = sj - lnD;                  // log(filtered)
      float val = logit + gumbel_from_idx(idx);
      if (val > bestv || (val == bestv && idx < bestidx)){
        bestv = val; bestlogit = logit; bestidx = idx;
      }
    }
  }
  #pragma unroll
  for (int off = 32; off; off >>= 1){
    float ov = __shfl_xor(bestv, off, 64);
    float ol = __shfl_xor(bestlogit, off, 64);
    unsigned int oi = (unsigned int)__shfl_xor((int)bestidx, off, 64);
    if (ov > bestv || (ov == bestv && oi < bestidx)){
      bestv = ov; bestlogit = ol; bestidx = oi;
    }
  }
  if (lane == 0){ rv[wave] = bestv; rl[wave] = bestlogit; ri[wave] = bestidx; }
  __syncthreads();
  if (t == 0){
    for (int w = 1; w < 16; ++w){
      if (rv[w] > rv[0] || (rv[w] == rv[0] && ri[w] < ri[0])){
        rv[0] = rv[w]; rl[0] = rl[w]; ri[0] = ri[w];
      }
    }
    out[N] = rl[0];                 // log_prob_action
    out[N + 1] = (float)ri[0];      // action_idx
  }
}

extern "C" void kernel_launch(void* const* d_in, const int* in_sizes, int n_in,
                              void* d_out, int out_size, void* d_ws, size_t ws_size,
                              hipStream_t stream){
  const float* cur  = (const float*)d_in[0];
  const float* ctx  = (const float*)d_in[1];
  const float* cand = (const float*)d_in[2];
  const float* Wq   = (const float*)d_in[3];
  const float* Wk   = (const float*)d_in[4];
  const int*   mask = (const int*)d_in[5];
  int N = in_sizes[5];
  float* out = (float*)d_out;

  char* ws = (char*)d_ws;
  unsigned int* scal_u  = (unsigned int*)ws;                  // 64B ([8]=done)
  float*        v       = (float*)(ws + 512);                 // 512B
  float*        zpart   = (float*)(ws + 1024);                // MAXB*4
  unsigned int* cnt     = (unsigned int*)(ws + 1536);         // MAXB*4
  float*        scores  = (float*)(ws + 4096);                // N*4, 16B-aligned
  char*         bufbase = ws + 4096 + (((size_t)N * 4 + 255) & ~255ull);
  float*        buf_s   = (float*)bufbase;                    // MAXB*SLOT*4
  unsigned int* buf_idx = (unsigned int*)(bufbase + (size_t)MAXB * SLOT * 4);

  int ktop = N / 2; if (ktop < 1) ktop = 1; if (ktop > 50) ktop = 50;
  int g_score = (N + 63) / 64;          // one 64-row tile per block
  int nb = (N + 4095) / 4096;           // 49 for N=200000
  if (nb > MAXB) nb = MAXB;             // (N fixed at 200000; guard only)

  k_prep<<<1, 256, 0, stream>>>(cur, ctx, Wq, Wk, v, scal_u);
  k_score<<<g_score, 256, 0, stream>>>(cand, mask, v, scores, out, N);
  k_tail<<<nb, 1024, 0, stream>>>(scores, scal_u, zpart, cnt,
                                  buf_idx, buf_s, out, N, ktop, nb);
}